// Round 8
// baseline (351.936 us; speedup 1.0000x reference)
//
#include <hip/hip_runtime.h>
#include <cmath>

#define CNUM 512
#define DNUM 128
#define BNUM 4096
#define EPSV 1e-5f
#define GPBLK 72            // (4096 + 512) / 64 split-K partial blocks

// ---- all intermediates in device globals: no d_ws dependence at all ----
__device__ float g_counts[CNUM];
__device__ float g_mean[CNUM * DNUM];
__device__ float g_lp[CNUM];
__device__ float g_G[DNUM * DNUM];
__device__ float g_Gp[GPBLK * DNUM * DNUM];   // split-K partials, 4.7 MB
__device__ float g_P[DNUM * DNUM];
__device__ float g_Pm[CNUM * DNUM];
__device__ float g_r[CNUM];
__device__ float g_q[BNUM];

// ---- class sums + counts, no global atomics: each block owns a dim-slice ----
__global__ __launch_bounds__(256) void k_csum(const float* __restrict__ z, const int* __restrict__ y) {
    const int t = threadIdx.x;
    const int bi = blockIdx.x;
    if (bi < 16) {
        __shared__ float acc[CNUM][8];        // 16 KB
        #pragma unroll
        for (int v = 0; v < 16; ++v) {
            int idx = t + v * 256;
            acc[idx >> 3][idx & 7] = 0.0f;
        }
        __syncthreads();
        const int d0 = bi * 8;
        #pragma unroll
        for (int i = 0; i < 16; ++i) {
            int s = i * 256 + t;
            int yy = y[s];
            const float4* zp = (const float4*)(z + (size_t)s * DNUM + d0);
            float4 a = zp[0], b = zp[1];
            float* dst = &acc[yy][0];
            atomicAdd(dst + 0, a.x); atomicAdd(dst + 1, a.y);
            atomicAdd(dst + 2, a.z); atomicAdd(dst + 3, a.w);
            atomicAdd(dst + 4, b.x); atomicAdd(dst + 5, b.y);
            atomicAdd(dst + 6, b.z); atomicAdd(dst + 7, b.w);
        }
        __syncthreads();
        #pragma unroll
        for (int v = 0; v < 2; ++v) {
            int c = t + v * 256;
            *(float4*)&g_mean[(size_t)c * DNUM + d0]     = *(float4*)&acc[c][0];
            *(float4*)&g_mean[(size_t)c * DNUM + d0 + 4] = *(float4*)&acc[c][4];
        }
    } else {
        __shared__ float cnt[CNUM];
        cnt[t] = 0.0f; cnt[t + 256] = 0.0f;
        __syncthreads();
        #pragma unroll
        for (int i = 0; i < 16; ++i) atomicAdd(&cnt[y[i * 256 + t]], 1.0f);
        __syncthreads();
        g_counts[t] = cnt[t];
        g_counts[t + 256] = cnt[t + 256];
    }
}

// ---------------- mean = sum/(n+eps); logprior ----------------
__global__ __launch_bounds__(256) void k_mean_prior(float logtot) {
    int idx = blockIdx.x * 256 + threadIdx.x;   // 65536 threads
    int c = idx >> 7;
    float cnt = g_counts[c] + EPSV;
    g_mean[idx] = g_mean[idx] / cnt;
    if (idx < CNUM) g_lp[idx] = logf(g_counts[idx] + EPSV) - logtot;
}

// ---- G split-K partial: rows [b*64, b*64+64) of X=[z; mean], weighted ----
__global__ __launch_bounds__(256) void k_gpart(const float* __restrict__ z) {
    __shared__ float xs[64][132];
    __shared__ float ws[64];
    const int t = threadIdx.x;
    const int R0 = blockIdx.x * 64;
    #pragma unroll
    for (int v = 0; v < 8; ++v) {
        int idx = t + v * 256;
        int r = idx >> 5, f4 = idx & 31;
        int row = R0 + r;
        float4 val;
        if (row < BNUM) {
            val = ((const float4*)z)[(size_t)row * 32 + f4];
            if (f4 == 0) ws[r] = 1.0f;
        } else {
            int c = row - BNUM;
            val = ((const float4*)g_mean)[(size_t)c * 32 + f4];
            if (f4 == 0) ws[r] = -(g_counts[c] + 2.0f * EPSV);
        }
        *(float4*)&xs[r][f4 * 4] = val;
    }
    __syncthreads();
    const int tx = t & 15, ty = t >> 4;
    float acc[8][8] = {};
    #pragma unroll
    for (int s = 0; s < 64; ++s) {
        const float4* pa = (const float4*)&xs[s][ty * 8];
        const float4* pb = (const float4*)&xs[s][tx * 8];
        float w = ws[s];
        float4 t0 = pa[0], t1 = pa[1];
        float4 u0 = pb[0], u1 = pb[1];
        float va[8] = {w * t0.x, w * t0.y, w * t0.z, w * t0.w, w * t1.x, w * t1.y, w * t1.z, w * t1.w};
        float vb[8] = {u0.x, u0.y, u0.z, u0.w, u1.x, u1.y, u1.z, u1.w};
        #pragma unroll
        for (int i = 0; i < 8; ++i)
            #pragma unroll
            for (int j = 0; j < 8; ++j)
                acc[i][j] += va[i] * vb[j];
    }
    float* gp = g_Gp + (size_t)blockIdx.x * DNUM * DNUM;
    #pragma unroll
    for (int i = 0; i < 8; ++i) {
        *(float4*)(gp + (size_t)(ty * 8 + i) * DNUM + tx * 8)     = make_float4(acc[i][0], acc[i][1], acc[i][2], acc[i][3]);
        *(float4*)(gp + (size_t)(ty * 8 + i) * DNUM + tx * 8 + 4) = make_float4(acc[i][4], acc[i][5], acc[i][6], acc[i][7]);
    }
}

// ---------------- reduce 72 partials -> g_G ----------------
__global__ __launch_bounds__(256) void k_greduce() {
    int idx = blockIdx.x * 256 + threadIdx.x;   // 16384 threads
    float s = 0.0f;
    #pragma unroll
    for (int p = 0; p < GPBLK; ++p) s += g_Gp[(size_t)p * DNUM * DNUM + idx];
    g_G[idx] = s;
}

// ---- blocked-panel Gauss-Jordan inverse: 16 steps of rank-8 updates ----
// Thread (ty,tx) owns 8x8 tile in VGPRs. Per step kb:
//  P1: pivot thread inverts its 8x8 block (serial, unrolled) -> dinv; a = Dinv
//  P2: col-panel (tx==kb): U = a@Dinv -> colp, a = -U
//      row-panel (ty==kb): publish old a -> rowp, a = Dinv@a
//  P3: interior: a -= U_tile @ oldrow_tile   (rank-8, 512 FMA/thread)
// Block algebra = verified scalar GJ with d->Dinv (order: U=A[i][k]D^-1 right,
// row D^-1 A[k][j] left). SPD leading blocks stay invertible -> no pivoting.
__global__ __launch_bounds__(256) void k_gj(float invtot2) {
    __shared__ float dinv[8][8];
    __shared__ float colp[128][8];
    __shared__ float rowp[8][128];
    const int tx = threadIdx.x & 15, ty = threadIdx.x >> 4;
    const int R = ty * 8, Cc = tx * 8;
    float a[8][8];
    #pragma unroll
    for (int i = 0; i < 8; ++i)
        #pragma unroll
        for (int j = 0; j < 8; ++j) {
            int gi = R + i, gj = Cc + j;
            float v = (g_G[gi * DNUM + gj] + g_G[gj * DNUM + gi]) * invtot2;
            if (gi == gj) v += EPSV;
            a[i][j] = v;
        }
    for (int kb = 0; kb < 16; ++kb) {
        // ---- P1: serial 8x8 inverse of pivot block ----
        if (ty == kb && tx == kb) {
            float m[8][8];
            #pragma unroll
            for (int i = 0; i < 8; ++i)
                #pragma unroll
                for (int j = 0; j < 8; ++j) m[i][j] = a[i][j];
            #pragma unroll
            for (int k = 0; k < 8; ++k) {
                float d = 1.0f / m[k][k];
                #pragma unroll
                for (int i = 0; i < 8; ++i) {
                    if (i == k) continue;
                    float c = m[i][k] * d;
                    #pragma unroll
                    for (int j = 0; j < 8; ++j)
                        if (j != k) m[i][j] -= c * m[k][j];
                }
                #pragma unroll
                for (int j = 0; j < 8; ++j) if (j != k) m[k][j] *= d;
                #pragma unroll
                for (int i = 0; i < 8; ++i) if (i != k) m[i][k] *= -d;
                m[k][k] = d;
            }
            #pragma unroll
            for (int i = 0; i < 8; ++i) {
                #pragma unroll
                for (int j = 0; j < 8; ++j) { dinv[i][j] = m[i][j]; a[i][j] = m[i][j]; }
            }
        }
        __syncthreads();
        // ---- P2: panels ----
        if (tx == kb && ty != kb) {            // column panel: U = a @ Dinv
            float u[8][8];
            #pragma unroll
            for (int i = 0; i < 8; ++i)
                #pragma unroll
                for (int kk = 0; kk < 8; ++kk) {
                    float s = 0.f;
                    #pragma unroll
                    for (int m = 0; m < 8; ++m) s += a[i][m] * dinv[m][kk];
                    u[i][kk] = s;
                }
            #pragma unroll
            for (int i = 0; i < 8; ++i) {
                *(float4*)&colp[R + i][0] = make_float4(u[i][0], u[i][1], u[i][2], u[i][3]);
                *(float4*)&colp[R + i][4] = make_float4(u[i][4], u[i][5], u[i][6], u[i][7]);
                #pragma unroll
                for (int kk = 0; kk < 8; ++kk) a[i][kk] = -u[i][kk];
            }
        }
        if (ty == kb && tx != kb) {            // row panel: publish old, a = Dinv @ a
            #pragma unroll
            for (int kk = 0; kk < 8; ++kk) {
                *(float4*)&rowp[kk][Cc]     = make_float4(a[kk][0], a[kk][1], a[kk][2], a[kk][3]);
                *(float4*)&rowp[kk][Cc + 4] = make_float4(a[kk][4], a[kk][5], a[kk][6], a[kk][7]);
            }
            float rn[8][8];
            #pragma unroll
            for (int kk = 0; kk < 8; ++kk)
                #pragma unroll
                for (int j = 0; j < 8; ++j) {
                    float s = 0.f;
                    #pragma unroll
                    for (int m = 0; m < 8; ++m) s += dinv[kk][m] * a[m][j];
                    rn[kk][j] = s;
                }
            #pragma unroll
            for (int kk = 0; kk < 8; ++kk)
                #pragma unroll
                for (int j = 0; j < 8; ++j) a[kk][j] = rn[kk][j];
        }
        __syncthreads();
        // ---- P3: rank-8 interior update ----
        if (ty != kb && tx != kb) {
            float cr[8][8];
            #pragma unroll
            for (int i = 0; i < 8; ++i) {
                float4 c0 = *(const float4*)&colp[R + i][0];
                float4 c1 = *(const float4*)&colp[R + i][4];
                cr[i][0] = c0.x; cr[i][1] = c0.y; cr[i][2] = c0.z; cr[i][3] = c0.w;
                cr[i][4] = c1.x; cr[i][5] = c1.y; cr[i][6] = c1.z; cr[i][7] = c1.w;
            }
            #pragma unroll
            for (int kk = 0; kk < 8; ++kk) {
                float4 r0 = *(const float4*)&rowp[kk][Cc];
                float4 r1 = *(const float4*)&rowp[kk][Cc + 4];
                float rr[8] = {r0.x, r0.y, r0.z, r0.w, r1.x, r1.y, r1.z, r1.w};
                #pragma unroll
                for (int i = 0; i < 8; ++i)
                    #pragma unroll
                    for (int j = 0; j < 8; ++j)
                        a[i][j] -= cr[i][kk] * rr[j];
            }
        }
        __syncthreads();                       // WAR: colp/rowp/dinv reused next kb
    }
    #pragma unroll
    for (int i = 0; i < 8; ++i) {
        *(float4*)(g_P + (size_t)(R + i) * DNUM + Cc)     = make_float4(a[i][0], a[i][1], a[i][2], a[i][3]);
        *(float4*)(g_P + (size_t)(R + i) * DNUM + Cc + 4) = make_float4(a[i][4], a[i][5], a[i][6], a[i][7]);
    }
}

// ---- fused X@P row-dot kernel: blocks 0..7 mean (Pm + r), 8..71 z (q) ----
__global__ __launch_bounds__(256) void k_xpq(const float* __restrict__ z) {
    __shared__ float xs[64][132];
    __shared__ float part[64][33];
    const int t = threadIdx.x;
    const int bi = blockIdx.x;
    const bool mmode = (bi < 8);
    const float* __restrict__ X = mmode ? (const float*)g_mean : z;
    const int row0 = mmode ? bi * 64 : (bi - 8) * 64;
    #pragma unroll
    for (int v = 0; v < 8; ++v) {
        int idx = t + v * 256;
        int r = idx >> 5, f4 = idx & 31;
        float4 val = ((const float4*)X)[(size_t)(row0 + r) * 32 + f4];
        *(float4*)&xs[r][f4 * 4] = val;
    }
    __syncthreads();
    int tx = t & 31, ty = t >> 5;
    float acc[8][4] = {};
    for (int e = 0; e < DNUM; ++e) {
        float4 pv = ((const float4*)g_P)[e * 32 + tx];
        #pragma unroll
        for (int i = 0; i < 8; ++i) {
            float xv = xs[ty * 8 + i][e];
            acc[i][0] += xv * pv.x; acc[i][1] += xv * pv.y;
            acc[i][2] += xv * pv.z; acc[i][3] += xv * pv.w;
        }
    }
    #pragma unroll
    for (int i = 0; i < 8; ++i) {
        int r = ty * 8 + i;
        if (mmode)
            *(float4*)&g_Pm[(size_t)(row0 + r) * DNUM + tx * 4] =
                make_float4(acc[i][0], acc[i][1], acc[i][2], acc[i][3]);
        part[r][tx] = acc[i][0] * xs[r][tx * 4 + 0] + acc[i][1] * xs[r][tx * 4 + 1]
                    + acc[i][2] * xs[r][tx * 4 + 2] + acc[i][3] * xs[r][tx * 4 + 3];
    }
    __syncthreads();
    if (t < 64) {
        float s = 0.f;
        #pragma unroll
        for (int x = 0; x < 32; ++x) s += part[t][x];
        if (mmode) g_r[row0 + t] = s;
        else       g_q[row0 + t] = s;
    }
}

// ---------------- out[b][c] = lp[c] - 0.5*q_b - 0.5*r_c + z_b . Pm_c ----------------
__global__ __launch_bounds__(256) void k_out(const float* __restrict__ z, float* __restrict__ out) {
    __shared__ float zs[64][65];
    __shared__ float ps[64][65];
    int t = threadIdx.x;
    int m0 = blockIdx.y * 64;      // sample rows
    int c0 = blockIdx.x * 64;      // class cols
    int tx = t & 15, ty = t >> 4;
    float acc[4][4] = {};
    for (int kc = 0; kc < 2; ++kc) {
        #pragma unroll
        for (int v = 0; v < 4; ++v) {
            int idx = t + v * 256;
            int r = idx >> 4, f4 = idx & 15;
            float4 zv = ((const float4*)z)[(size_t)(m0 + r) * 32 + kc * 16 + f4];
            zs[r][f4 * 4 + 0] = zv.x; zs[r][f4 * 4 + 1] = zv.y;
            zs[r][f4 * 4 + 2] = zv.z; zs[r][f4 * 4 + 3] = zv.w;
            float4 pv = ((const float4*)g_Pm)[(size_t)(c0 + r) * 32 + kc * 16 + f4];
            ps[r][f4 * 4 + 0] = pv.x; ps[r][f4 * 4 + 1] = pv.y;
            ps[r][f4 * 4 + 2] = pv.z; ps[r][f4 * 4 + 3] = pv.w;
        }
        __syncthreads();
        #pragma unroll 8
        for (int kk = 0; kk < 64; ++kk) {
            float za[4], pb[4];
            #pragma unroll
            for (int i = 0; i < 4; ++i) za[i] = zs[ty * 4 + i][kk];
            #pragma unroll
            for (int j = 0; j < 4; ++j) pb[j] = ps[tx * 4 + j][kk];
            #pragma unroll
            for (int i = 0; i < 4; ++i)
                #pragma unroll
                for (int j = 0; j < 4; ++j)
                    acc[i][j] += za[i] * pb[j];
        }
        __syncthreads();
    }
    int cbase = c0 + tx * 4;
    float4 lp4 = *(const float4*)(g_lp + cbase);
    float4 rv4 = *(const float4*)(g_r + cbase);
    #pragma unroll
    for (int i = 0; i < 4; ++i) {
        int row = m0 + ty * 4 + i;
        float qv = g_q[row];
        float4 o;
        o.x = acc[i][0] + lp4.x - 0.5f * (qv + rv4.x);
        o.y = acc[i][1] + lp4.y - 0.5f * (qv + rv4.y);
        o.z = acc[i][2] + lp4.z - 0.5f * (qv + rv4.z);
        o.w = acc[i][3] + lp4.w - 0.5f * (qv + rv4.w);
        *(float4*)&out[(size_t)row * CNUM + cbase] = o;
    }
}

extern "C" void kernel_launch(void* const* d_in, const int* in_sizes, int n_in,
                              void* d_out, int out_size, void* d_ws, size_t ws_size,
                              hipStream_t stream) {
    const float* z = (const float*)d_in[0];
    const int* y = (const int*)d_in[1];
    float* out = (float*)d_out;
    const int B = in_sizes[0] / DNUM;                 // 4096
    const float total = (float)B + (float)CNUM * EPSV;
    const float logtot = logf(total);

    k_csum<<<17, 256, 0, stream>>>(z, y);
    k_mean_prior<<<(CNUM * DNUM) / 256, 256, 0, stream>>>(logtot);
    k_gpart<<<GPBLK, 256, 0, stream>>>(z);
    k_greduce<<<DNUM * DNUM / 256, 256, 0, stream>>>();
    k_gj<<<1, 256, 0, stream>>>(0.5f / total);
    k_xpq<<<GPBLK, 256, 0, stream>>>(z);
    k_out<<<dim3(CNUM / 64, B / 64), 256, 0, stream>>>(z, out);
}

// Round 9
// 210.615 us; speedup vs baseline: 1.6710x; 1.6710x over previous
//
#include <hip/hip_runtime.h>
#include <cmath>

#define CNUM 512
#define DNUM 128
#define BNUM 4096
#define EPSV 1e-5f
#define GPBLK 72            // (4096 + 512) / 64 split-K partial blocks

// ---- all intermediates in device globals: no d_ws dependence at all ----
__device__ float g_counts[CNUM];
__device__ float g_mean[CNUM * DNUM];
__device__ float g_lp[CNUM];
__device__ float g_G[DNUM * DNUM];
__device__ float g_Gp[GPBLK * DNUM * DNUM];   // split-K partials, 4.7 MB
__device__ float g_P[DNUM * DNUM];
__device__ float g_Pm[CNUM * DNUM];
__device__ float g_r[CNUM];
__device__ float g_q[BNUM];

// ---- class sums + counts + mean + logprior, no global atomics ----
// Every block builds the 512-bin count histogram (cheap). Blocks 0..15 own
// dims [bi*8, bi*8+8) of all 512 class sums (LDS), divide by (n+eps), write
// mean slice. Block 16 writes counts + logprior.
__global__ __launch_bounds__(256) void k_csum(const float* __restrict__ z, const int* __restrict__ y,
                                              float logtot) {
    const int t = threadIdx.x;
    const int bi = blockIdx.x;
    __shared__ float cnt[CNUM];
    cnt[t] = 0.0f; cnt[t + 256] = 0.0f;
    __syncthreads();
    #pragma unroll
    for (int i = 0; i < 16; ++i) atomicAdd(&cnt[y[i * 256 + t]], 1.0f);
    __syncthreads();
    if (bi < 16) {
        __shared__ float acc[CNUM][8];        // 16 KB
        #pragma unroll
        for (int v = 0; v < 16; ++v) {
            int idx = t + v * 256;
            acc[idx >> 3][idx & 7] = 0.0f;
        }
        __syncthreads();
        const int d0 = bi * 8;
        #pragma unroll
        for (int i = 0; i < 16; ++i) {
            int s = i * 256 + t;
            int yy = y[s];
            const float4* zp = (const float4*)(z + (size_t)s * DNUM + d0);
            float4 a = zp[0], b = zp[1];
            float* dst = &acc[yy][0];
            atomicAdd(dst + 0, a.x); atomicAdd(dst + 1, a.y);
            atomicAdd(dst + 2, a.z); atomicAdd(dst + 3, a.w);
            atomicAdd(dst + 4, b.x); atomicAdd(dst + 5, b.y);
            atomicAdd(dst + 6, b.z); atomicAdd(dst + 7, b.w);
        }
        __syncthreads();
        #pragma unroll
        for (int v = 0; v < 2; ++v) {
            int c = t + v * 256;
            float inv = 1.0f / (cnt[c] + EPSV);
            float4 a0 = *(float4*)&acc[c][0];
            float4 a1 = *(float4*)&acc[c][4];
            *(float4*)&g_mean[(size_t)c * DNUM + d0]     = make_float4(a0.x * inv, a0.y * inv, a0.z * inv, a0.w * inv);
            *(float4*)&g_mean[(size_t)c * DNUM + d0 + 4] = make_float4(a1.x * inv, a1.y * inv, a1.z * inv, a1.w * inv);
        }
    } else {
        #pragma unroll
        for (int v = 0; v < 2; ++v) {
            int c = t + v * 256;
            g_counts[c] = cnt[c];
            g_lp[c] = logf(cnt[c] + EPSV) - logtot;
        }
    }
}

// ---- G split-K partial: rows [b*64, b*64+64) of X=[z; mean], weighted ----
// G = sum_b z z^T - sum_c (n_c+2eps) m_c m_c^T  (derived: s_c=(n_c+eps)m_c)
__global__ __launch_bounds__(256) void k_gpart(const float* __restrict__ z) {
    __shared__ float xs[64][132];
    __shared__ float ws[64];
    const int t = threadIdx.x;
    const int R0 = blockIdx.x * 64;
    #pragma unroll
    for (int v = 0; v < 8; ++v) {
        int idx = t + v * 256;
        int r = idx >> 5, f4 = idx & 31;
        int row = R0 + r;
        float4 val;
        if (row < BNUM) {
            val = ((const float4*)z)[(size_t)row * 32 + f4];
            if (f4 == 0) ws[r] = 1.0f;
        } else {
            int c = row - BNUM;
            val = ((const float4*)g_mean)[(size_t)c * 32 + f4];
            if (f4 == 0) ws[r] = -(g_counts[c] + 2.0f * EPSV);
        }
        *(float4*)&xs[r][f4 * 4] = val;
    }
    __syncthreads();
    const int tx = t & 15, ty = t >> 4;
    float acc[8][8] = {};
    #pragma unroll
    for (int s = 0; s < 64; ++s) {
        const float4* pa = (const float4*)&xs[s][ty * 8];
        const float4* pb = (const float4*)&xs[s][tx * 8];
        float w = ws[s];
        float4 t0 = pa[0], t1 = pa[1];
        float4 u0 = pb[0], u1 = pb[1];
        float va[8] = {w * t0.x, w * t0.y, w * t0.z, w * t0.w, w * t1.x, w * t1.y, w * t1.z, w * t1.w};
        float vb[8] = {u0.x, u0.y, u0.z, u0.w, u1.x, u1.y, u1.z, u1.w};
        #pragma unroll
        for (int i = 0; i < 8; ++i)
            #pragma unroll
            for (int j = 0; j < 8; ++j)
                acc[i][j] += va[i] * vb[j];
    }
    float* gp = g_Gp + (size_t)blockIdx.x * DNUM * DNUM;
    #pragma unroll
    for (int i = 0; i < 8; ++i) {
        *(float4*)(gp + (size_t)(ty * 8 + i) * DNUM + tx * 8)     = make_float4(acc[i][0], acc[i][1], acc[i][2], acc[i][3]);
        *(float4*)(gp + (size_t)(ty * 8 + i) * DNUM + tx * 8 + 4) = make_float4(acc[i][4], acc[i][5], acc[i][6], acc[i][7]);
    }
}

// ---------------- reduce 72 partials -> g_G ----------------
__global__ __launch_bounds__(256) void k_greduce() {
    int idx = blockIdx.x * 256 + threadIdx.x;   // 16384 threads
    float s = 0.0f;
    #pragma unroll
    for (int p = 0; p < GPBLK; ++p) s += g_Gp[(size_t)p * DNUM * DNUM + idx];
    g_G[idx] = s;
}

// ---- register-tile Gauss-Jordan inverse (fused symmetrize+eps load) ----
// R7 version (measured 62us, VGPR 96, no spills). 256 threads; thread (ty,tx)
// owns an 8x8 tile in VGPRs; per pivot: publish col/row via LDS, 2 barriers.
__global__ __launch_bounds__(256) void k_gj(float invtot2) {
    __shared__ float rowk[128], colk[128];
    __shared__ float dsh;
    const int tx = threadIdx.x & 15, ty = threadIdx.x >> 4;
    const int R = ty * 8, Cc = tx * 8;
    float a[8][8];
    #pragma unroll
    for (int i = 0; i < 8; ++i)
        #pragma unroll
        for (int j = 0; j < 8; ++j) {
            int gi = R + i, gj = Cc + j;
            float v = (g_G[gi * DNUM + gj] + g_G[gj * DNUM + gi]) * invtot2;
            if (gi == gj) v += EPSV;
            a[i][j] = v;
        }
    if (tx == 0 && ty == 0) dsh = 1.0f / a[0][0];
    __syncthreads();
    for (int kb = 0; kb < 16; ++kb) {
        #pragma unroll
        for (int ko = 0; ko < 8; ++ko) {
            const int k = kb * 8 + ko;
            float d = dsh;
            if (tx == kb) {                        // new column k: A'[i][k] = -A[i][k]*d
                float cv[8];
                #pragma unroll
                for (int i = 0; i < 8; ++i) {
                    int gi = R + i;
                    float v = -a[i][ko] * d;
                    if (gi == k) v = 0.0f;         // mask pivot slot
                    cv[i] = v;
                    if (gi != k) a[i][ko] = v;
                }
                *(float4*)&colk[R]     = make_float4(cv[0], cv[1], cv[2], cv[3]);
                *(float4*)&colk[R + 4] = make_float4(cv[4], cv[5], cv[6], cv[7]);
            }
            if (ty == kb) {                        // old row k (pivot slot zeroed)
                float rv[8];
                #pragma unroll
                for (int j = 0; j < 8; ++j) {
                    int gj = Cc + j;
                    rv[j] = (gj == k) ? 0.0f : a[ko][j];
                }
                *(float4*)&rowk[Cc]     = make_float4(rv[0], rv[1], rv[2], rv[3]);
                *(float4*)&rowk[Cc + 4] = make_float4(rv[4], rv[5], rv[6], rv[7]);
            }
            __syncthreads();
            float4 c0 = *(const float4*)&colk[R], c1 = *(const float4*)&colk[R + 4];
            float4 r0 = *(const float4*)&rowk[Cc], r1 = *(const float4*)&rowk[Cc + 4];
            float cr[8] = {c0.x, c0.y, c0.z, c0.w, c1.x, c1.y, c1.z, c1.w};
            float rr[8] = {r0.x, r0.y, r0.z, r0.w, r1.x, r1.y, r1.z, r1.w};
            #pragma unroll
            for (int i = 0; i < 8; ++i)
                #pragma unroll
                for (int j = 0; j < 8; ++j)
                    a[i][j] += cr[i] * rr[j];
            if (ty == kb) {                        // scale row k (untouched by rank-1)
                #pragma unroll
                for (int j = 0; j < 8; ++j) { int gj = Cc + j; if (gj != k) a[ko][j] *= d; }
                if (tx == kb) a[ko][ko] = d;
            }
            if (ko < 7) { if (ty == kb && tx == kb) dsh = 1.0f / a[ko + 1][ko + 1]; }
            else        { if (kb < 15 && ty == kb + 1 && tx == kb + 1) dsh = 1.0f / a[0][0]; }
            __syncthreads();
        }
    }
    #pragma unroll
    for (int i = 0; i < 8; ++i) {
        *(float4*)(g_P + (size_t)(R + i) * DNUM + Cc)     = make_float4(a[i][0], a[i][1], a[i][2], a[i][3]);
        *(float4*)(g_P + (size_t)(R + i) * DNUM + Cc + 4) = make_float4(a[i][4], a[i][5], a[i][6], a[i][7]);
    }
}

// ---- fused X@P row-dot kernel: blocks 0..7 mean (Pm + r), 8..71 z (q) ----
__global__ __launch_bounds__(256) void k_xpq(const float* __restrict__ z) {
    __shared__ float xs[64][132];
    __shared__ float part[64][33];
    const int t = threadIdx.x;
    const int bi = blockIdx.x;
    const bool mmode = (bi < 8);
    const float* __restrict__ X = mmode ? (const float*)g_mean : z;
    const int row0 = mmode ? bi * 64 : (bi - 8) * 64;
    #pragma unroll
    for (int v = 0; v < 8; ++v) {
        int idx = t + v * 256;
        int r = idx >> 5, f4 = idx & 31;
        float4 val = ((const float4*)X)[(size_t)(row0 + r) * 32 + f4];
        *(float4*)&xs[r][f4 * 4] = val;
    }
    __syncthreads();
    int tx = t & 31, ty = t >> 5;
    float acc[8][4] = {};
    for (int e = 0; e < DNUM; ++e) {
        float4 pv = ((const float4*)g_P)[e * 32 + tx];
        #pragma unroll
        for (int i = 0; i < 8; ++i) {
            float xv = xs[ty * 8 + i][e];
            acc[i][0] += xv * pv.x; acc[i][1] += xv * pv.y;
            acc[i][2] += xv * pv.z; acc[i][3] += xv * pv.w;
        }
    }
    #pragma unroll
    for (int i = 0; i < 8; ++i) {
        int r = ty * 8 + i;
        if (mmode)
            *(float4*)&g_Pm[(size_t)(row0 + r) * DNUM + tx * 4] =
                make_float4(acc[i][0], acc[i][1], acc[i][2], acc[i][3]);
        part[r][tx] = acc[i][0] * xs[r][tx * 4 + 0] + acc[i][1] * xs[r][tx * 4 + 1]
                    + acc[i][2] * xs[r][tx * 4 + 2] + acc[i][3] * xs[r][tx * 4 + 3];
    }
    __syncthreads();
    if (t < 64) {
        float s = 0.f;
        #pragma unroll
        for (int x = 0; x < 32; ++x) s += part[t][x];
        if (mmode) g_r[row0 + t] = s;
        else       g_q[row0 + t] = s;
    }
}

// ---------------- out[b][c] = lp[c] - 0.5*q_b - 0.5*r_c + z_b . Pm_c ----------------
__global__ __launch_bounds__(256) void k_out(const float* __restrict__ z, float* __restrict__ out) {
    __shared__ float zs[64][65];
    __shared__ float ps[64][65];
    int t = threadIdx.x;
    int m0 = blockIdx.y * 64;      // sample rows
    int c0 = blockIdx.x * 64;      // class cols
    int tx = t & 15, ty = t >> 4;
    float acc[4][4] = {};
    for (int kc = 0; kc < 2; ++kc) {
        #pragma unroll
        for (int v = 0; v < 4; ++v) {
            int idx = t + v * 256;
            int r = idx >> 4, f4 = idx & 15;
            float4 zv = ((const float4*)z)[(size_t)(m0 + r) * 32 + kc * 16 + f4];
            zs[r][f4 * 4 + 0] = zv.x; zs[r][f4 * 4 + 1] = zv.y;
            zs[r][f4 * 4 + 2] = zv.z; zs[r][f4 * 4 + 3] = zv.w;
            float4 pv = ((const float4*)g_Pm)[(size_t)(c0 + r) * 32 + kc * 16 + f4];
            ps[r][f4 * 4 + 0] = pv.x; ps[r][f4 * 4 + 1] = pv.y;
            ps[r][f4 * 4 + 2] = pv.z; ps[r][f4 * 4 + 3] = pv.w;
        }
        __syncthreads();
        #pragma unroll 8
        for (int kk = 0; kk < 64; ++kk) {
            float za[4], pb[4];
            #pragma unroll
            for (int i = 0; i < 4; ++i) za[i] = zs[ty * 4 + i][kk];
            #pragma unroll
            for (int j = 0; j < 4; ++j) pb[j] = ps[tx * 4 + j][kk];
            #pragma unroll
            for (int i = 0; i < 4; ++i)
                #pragma unroll
                for (int j = 0; j < 4; ++j)
                    acc[i][j] += za[i] * pb[j];
        }
        __syncthreads();
    }
    int cbase = c0 + tx * 4;
    float4 lp4 = *(const float4*)(g_lp + cbase);
    float4 rv4 = *(const float4*)(g_r + cbase);
    #pragma unroll
    for (int i = 0; i < 4; ++i) {
        int row = m0 + ty * 4 + i;
        float qv = g_q[row];
        float4 o;
        o.x = acc[i][0] + lp4.x - 0.5f * (qv + rv4.x);
        o.y = acc[i][1] + lp4.y - 0.5f * (qv + rv4.y);
        o.z = acc[i][2] + lp4.z - 0.5f * (qv + rv4.z);
        o.w = acc[i][3] + lp4.w - 0.5f * (qv + rv4.w);
        *(float4*)&out[(size_t)row * CNUM + cbase] = o;
    }
}

extern "C" void kernel_launch(void* const* d_in, const int* in_sizes, int n_in,
                              void* d_out, int out_size, void* d_ws, size_t ws_size,
                              hipStream_t stream) {
    const float* z = (const float*)d_in[0];
    const int* y = (const int*)d_in[1];
    float* out = (float*)d_out;
    const int B = in_sizes[0] / DNUM;                 // 4096
    const float total = (float)B + (float)CNUM * EPSV;
    const float logtot = logf(total);

    k_csum<<<17, 256, 0, stream>>>(z, y, logtot);
    k_gpart<<<GPBLK, 256, 0, stream>>>(z);
    k_greduce<<<DNUM * DNUM / 256, 256, 0, stream>>>();
    k_gj<<<1, 256, 0, stream>>>(0.5f / total);
    k_xpq<<<GPBLK, 256, 0, stream>>>(z);
    k_out<<<dim3(CNUM / 64, B / 64), 256, 0, stream>>>(z, out);
}